// Round 13
// baseline (95.426 us; speedup 1.0000x reference)
//
#include <hip/hip_runtime.h>

#define HID 256
#define K27 27

typedef __attribute__((ext_vector_type(8))) short    bf16x8;
typedef __attribute__((ext_vector_type(4))) float    f32x4;
typedef __attribute__((ext_vector_type(4))) unsigned u32x4;

static __device__ __forceinline__ unsigned short f2bf(float f) {
    union { float f; unsigned u; } v; v.f = f;   // cold path only (staging)
    return (unsigned short)((v.u + 0x7FFFu + ((v.u >> 16) & 1u)) >> 16);
}
static __device__ __forceinline__ unsigned pack2bf(float lo, float hi) {
    unsigned r;
    asm("v_cvt_pk_bf16_f32 %0, %1, %2" : "=v"(r) : "v"(lo), "v"(hi));
    return r;
}
static __device__ __forceinline__ bf16x8 as_bf16x8(u32x4 u) {
    return __builtin_bit_cast(bf16x8, u);
}
static __device__ __forceinline__ bf16x8 frag1(unsigned u) {
    u32x4 t = {u, 0u, 0u, 0u};
    return __builtin_bit_cast(bf16x8, t);
}
static __device__ __forceinline__ float lk(float x) {   // leaky_relu(0.01)
    return fmaxf(x, 0.01f * x);
}
// s += dpp_perm(s): VALU-only cross-lane add (verified v7/v10)
#define DPP_ADD(s, ctrl) \
    s += __builtin_bit_cast(float, __builtin_amdgcn_update_dpp( \
            0, __builtin_bit_cast(int, s), ctrl, 0xF, 0xF, true))

// v12 = v10 (verified 78us) + manual software pipelining of the iteration-head
// mapping/pos loads using NAMED SCALARS ONLY (no loop-carried arrays -> no
// alloca; no unroll pragma -> no wholesale reschedule). Next-iter loads issue
// before the kc loop (~1500cy cover) and rotate into place at the tail.
__global__ __launch_bounds__(256, 4) void mapnet_v12(
    const float* __restrict__ pos,      // (P,3)
    const int*   __restrict__ mapping,  // (P,2)
    const float* __restrict__ feats,    // (3,512,512)
    const float* __restrict__ W1,       // (256,3)
    const float* __restrict__ b1,       // (256)
    const float* __restrict__ W2,       // (27,256)
    const float* __restrict__ b2,       // (27)
    float* __restrict__ out)            // (P)
{
    __shared__ unsigned sW1f[16][64];   // [jt][lane]: pack2bf(W1val,0)  (4 KB)
    __shared__ bf16x8   sB[16][64];     // [kc*2+nt][lane]: L2 B-frags   (16 KB)

    const int tid = threadIdx.x;

    // ---- stage L1 A-fragments: lane (g,cc) of tile jt holds W1[16jt+cc][g] (g=3 -> b1)
    for (int e = tid; e < 1024; e += 256) {
        const int jt = e >> 6, l = e & 63;
        const int gg = l >> 4, cc = l & 15;
        const int j = jt * 16 + cc;
        const float val = (gg < 3) ? W1[3 * j + gg] : b1[j];
        sW1f[jt][l] = pack2bf(val, 0.0f);
    }
    // ---- stage L2 B-fragments, j-map matching L1 output: j = 32kc+16(e>>2)+4g+(e&3)
    for (int e = tid; e < 1024; e += 256) {
        const int kcnt = e >> 6, l = e & 63;
        const int kc = kcnt >> 1, nt = kcnt & 1;
        const int gg = l >> 4, cc = l & 15;
        const int n = nt * 16 + cc;
        const int jbase = kc * 32 + 4 * gg;
        u32x4 bb;
        #pragma unroll
        for (int i = 0; i < 4; ++i) {
            const int jlo = jbase + 16 * (i >> 1) + 2 * (i & 1);
            float f0 = 0.f, f1 = 0.f;
            if (n < K27) { f0 = W2[n * HID + jlo]; f1 = W2[n * HID + jlo + 1]; }
            bb[i] = (unsigned)f2bf(f0) | ((unsigned)f2bf(f1) << 16);
        }
        sB[kcnt][l] = as_bf16x8(bb);
    }
    __syncthreads();

    const int lane = tid & 63, wid = tid >> 6;
    const int g = lane >> 4, col = lane & 15;

    const float b2A = b2[col];
    const float b2B = (col < K27 - 16) ? b2[16 + col] : 0.0f;
    const int kA = col;
    const int cA = kA/9, dyA = (kA%9)/3 - 1, dxA = (kA%9)%3 - 1;
    const int kB = min(16 + col, K27 - 1);          // clamped -> valid addr; accB==0 there
    const int cB = kB/9, dyB = (kB%9)/3 - 1, dxB = (kB%9)%3 - 1;

    const float* fbaseA = feats + cA * (512*512);
    const float* fbaseB = feats + cB * (512*512);
    const int2*  map2   = (const int2*)mapping;

    const int w = blockIdx.x * 4 + wid;             // 0..8191

    // ---- prologue: iter-0 mapping (8 x int2) + pos (6 floats), named scalars
    const int pb0 = (w * 8) * 16, pb1 = pb0 + 16;
    int2 cm0 = map2[pb0 + g*4 + 0], cm1 = map2[pb0 + g*4 + 1];
    int2 cm2 = map2[pb0 + g*4 + 2], cm3 = map2[pb0 + g*4 + 3];
    int2 cm4 = map2[pb1 + g*4 + 0], cm5 = map2[pb1 + g*4 + 1];
    int2 cm6 = map2[pb1 + g*4 + 2], cm7 = map2[pb1 + g*4 + 3];
    float ca0 = pos[3*(pb0+col)], ca1 = pos[3*(pb0+col)+1], ca2 = pos[3*(pb0+col)+2];
    float cb0 = pos[3*(pb1+col)], cb1 = pos[3*(pb1+col)+1], cb2 = pos[3*(pb1+col)+2];

    for (int it = 0; it < 4; ++it) {
        const int tb0 = (w * 8 + it * 2) * 16, tb1 = tb0 + 16;

        const float v0 = (g == 0) ? ca0 : (g == 1) ? ca1 : (g == 2) ? ca2 : 1.0f;
        const float v1 = (g == 0) ? cb0 : (g == 1) ? cb1 : (g == 2) ? cb2 : 1.0f;
        const bf16x8 pB0 = frag1(pack2bf(v0, 0.0f));
        const bf16x8 pB1 = frag1(pack2bf(v1, 0.0f));

        // ---- gathers for CURRENT iter (mapping already in registers) ----
        float fvA[2][4], fvB[2][4];
        #pragma unroll
        for (int tt = 0; tt < 2; ++tt) {
            #pragma unroll
            for (int r = 0; r < 4; ++r) {
                const int2 mp = (tt == 0)
                    ? ((r == 0) ? cm0 : (r == 1) ? cm1 : (r == 2) ? cm2 : cm3)
                    : ((r == 0) ? cm4 : (r == 1) ? cm5 : (r == 2) ? cm6 : cm7);
                const int my = mp.x, mx = mp.y;
                int y  = my + dyA, x  = mx + dxA;
                int yc = min(max(y,0),511), xc = min(max(x,0),511);
                float f = fbaseA[yc*512 + xc];
                fvA[tt][r] = (((unsigned)y | (unsigned)x) < 512u) ? f : 0.f;
                int y2 = my + dyB, x2 = mx + dxB;
                int yc2 = min(max(y2,0),511), xc2 = min(max(x2,0),511);
                float f2 = fbaseB[yc2*512 + xc2];
                fvB[tt][r] = (((unsigned)y2 | (unsigned)x2) < 512u) ? f2 : 0.f;
            }
        }

        // ---- issue NEXT-iter mapping+pos loads (latency hides under kc loop)
        const int itn = (it < 3) ? (it + 1) : it;   // last iter: reload self
        const int nb0 = (w * 8 + itn * 2) * 16, nb1 = nb0 + 16;
        int2 nm0 = map2[nb0 + g*4 + 0], nm1 = map2[nb0 + g*4 + 1];
        int2 nm2 = map2[nb0 + g*4 + 2], nm3 = map2[nb0 + g*4 + 3];
        int2 nm4 = map2[nb1 + g*4 + 0], nm5 = map2[nb1 + g*4 + 1];
        int2 nm6 = map2[nb1 + g*4 + 2], nm7 = map2[nb1 + g*4 + 3];
        float na0 = pos[3*(nb0+col)], na1 = pos[3*(nb0+col)+1], na2 = pos[3*(nb0+col)+2];
        float nb0f = pos[3*(nb1+col)], nb1f = pos[3*(nb1+col)+1], nb2f = pos[3*(nb1+col)+2];

        f32x4 acc00 = {b2A,b2A,b2A,b2A}, acc01 = {b2B,b2B,b2B,b2B};
        f32x4 acc10 = {b2A,b2A,b2A,b2A}, acc11 = {b2B,b2B,b2B,b2B};
        const f32x4 zero = {0.f, 0.f, 0.f, 0.f};

        #pragma unroll
        for (int kc = 0; kc < 8; ++kc) {
            const bf16x8 wA0 = frag1(sW1f[2*kc    ][lane]);
            const bf16x8 wA1 = frag1(sW1f[2*kc + 1][lane]);

            // L1: h[j][px]; lane holds j = 16jt + 4g + reg, px = col
            const f32x4 c00 = __builtin_amdgcn_mfma_f32_16x16x32_bf16(wA0, pB0, zero, 0,0,0);
            const f32x4 c01 = __builtin_amdgcn_mfma_f32_16x16x32_bf16(wA1, pB0, zero, 0,0,0);
            const f32x4 c10 = __builtin_amdgcn_mfma_f32_16x16x32_bf16(wA0, pB1, zero, 0,0,0);
            const f32x4 c11 = __builtin_amdgcn_mfma_f32_16x16x32_bf16(wA1, pB1, zero, 0,0,0);

            // leaky + pack -> L2 A-fragment
            u32x4 a0, a1;
            a0[0] = pack2bf(lk(c00[0]), lk(c00[1]));
            a0[1] = pack2bf(lk(c00[2]), lk(c00[3]));
            a0[2] = pack2bf(lk(c01[0]), lk(c01[1]));
            a0[3] = pack2bf(lk(c01[2]), lk(c01[3]));
            a1[0] = pack2bf(lk(c10[0]), lk(c10[1]));
            a1[1] = pack2bf(lk(c10[2]), lk(c10[3]));
            a1[2] = pack2bf(lk(c11[0]), lk(c11[1]));
            a1[3] = pack2bf(lk(c11[2]), lk(c11[3]));
            const bf16x8 av0 = as_bf16x8(a0);
            const bf16x8 av1 = as_bf16x8(a1);

            const bf16x8 bv0 = sB[kc*2    ][lane];
            const bf16x8 bv1 = sB[kc*2 + 1][lane];
            acc00 = __builtin_amdgcn_mfma_f32_16x16x32_bf16(av0, bv0, acc00, 0,0,0);
            acc01 = __builtin_amdgcn_mfma_f32_16x16x32_bf16(av0, bv1, acc01, 0,0,0);
            acc10 = __builtin_amdgcn_mfma_f32_16x16x32_bf16(av1, bv0, acc10, 0,0,0);
            acc11 = __builtin_amdgcn_mfma_f32_16x16x32_bf16(av1, bv1, acc11, 0,0,0);
        }

        // ---- combine: col=lane&15 (k27), row=g*4+r (pixel); DPP 16-lane sum ----
        #pragma unroll
        for (int tt = 0; tt < 2; ++tt) {
            const int tb = tt ? tb1 : tb0;
            const f32x4 aA = tt ? acc10 : acc00;
            const f32x4 aB = tt ? acc11 : acc01;
            #pragma unroll
            for (int r = 0; r < 4; ++r) {
                float s = aA[r] * fvA[tt][r] + aB[r] * fvB[tt][r];
                DPP_ADD(s, 0xB1);    // quad_perm(1,0,3,2) : xor 1
                DPP_ADD(s, 0x4E);    // quad_perm(2,3,0,1) : xor 2
                DPP_ADD(s, 0x124);   // row_ror:4
                DPP_ADD(s, 0x128);   // row_ror:8
                if (col == r) out[tb + g*4 + r] = s;
            }
        }

        // ---- rotate pipeline scalars
        cm0 = nm0; cm1 = nm1; cm2 = nm2; cm3 = nm3;
        cm4 = nm4; cm5 = nm5; cm6 = nm6; cm7 = nm7;
        ca0 = na0; ca1 = na1; ca2 = na2;
        cb0 = nb0f; cb1 = nb1f; cb2 = nb2f;
    }
}

extern "C" void kernel_launch(void* const* d_in, const int* in_sizes, int n_in,
                              void* d_out, int out_size, void* d_ws, size_t ws_size,
                              hipStream_t stream) {
    const float* pos     = (const float*)d_in[0];
    const int*   mapping = (const int*)d_in[1];
    const float* feats   = (const float*)d_in[2];
    // d_in[3] = depth, unused
    const float* W1      = (const float*)d_in[4];
    const float* b1      = (const float*)d_in[5];
    const float* W2      = (const float*)d_in[6];
    const float* b2      = (const float*)d_in[7];
    float* out = (float*)d_out;

    // P = 1024*1024: 65536 tiles; 2048 blocks x 4 waves x 8 tiles
    mapnet_v12<<<2048, 256, 0, stream>>>(pos, mapping, feats, W1, b1, W2, b2, out);
}